// Round 4
// baseline (2128.183 us; speedup 1.0000x reference)
//
#include <hip/hip_runtime.h>
#include <hip/hip_bf16.h>
#include <type_traits>

// PointNetConv on MI355X (gfx950) — round 4.
//   K0 detect : sniff dtype of x (bf16 vs f32) -> flag   [measured r2/r3: f32 path active]
//   deg = 0 via hipMemsetAsync
//   K2 hist   : deg[col]++ (atomicAdd)
//   K3 scan   : 3-phase multi-block exclusive scan -> start, cursor
//   K4 scatter: srow[cursor[col]++] = row
//   K5 node_gemm<T,false>: xw1b(bf16, in d_out) = x @ W1x + b1
//   K6 pernode<T>: one wave per node; 32 edges/iter (2 MFMA row-tiles sharing
//                  B-fragment LDS reads); running max in regs; no atomics.
//   K7 node_gemm<T,true> : d_out = T(maxbf + x @ Wr + br)
//
// ws: maxbf N*128 bf16 (12.8MB) | srow E int (6.4MB) | deg N | start N+1 |
//     cursor N | flag 1 | tsum 256 | texcl 256        (~20 MB total)

typedef __bf16 bf16_t;
typedef __bf16 bf16x8 __attribute__((ext_vector_type(8)));
typedef float  f32x4  __attribute__((ext_vector_type(4)));

__global__ void detect_kernel(const unsigned* __restrict__ xw, int* __restrict__ flag) {
  int lane = threadIdx.x;            // 64 threads
  int cnt = 0;
#pragma unroll
  for (int i = 0; i < 4; ++i) {
    unsigned w = xw[lane * 4 + i];
    unsigned e = (w >> 7) & 0xFFu;   // exponent of LOW bf16 half
    cnt += (e >= 0x68u && e <= 0x88u) ? 1 : 0;
  }
#pragma unroll
  for (int off = 32; off > 0; off >>= 1) cnt += __shfl_down(cnt, off, 64);
  if (lane == 0) *flag = (cnt >= 128) ? 0 : 1;   // 0 = bf16, 1 = f32
}

__global__ __launch_bounds__(256) void hist_kernel(const int* __restrict__ eidx,
                                                   int* __restrict__ deg, int E) {
  int i = blockIdx.x * 256 + threadIdx.x;
  if (i < E) atomicAdd(&deg[eidx[E + i]], 1);
}

// --- 3-phase scan (N <= 256*256) ---
__global__ __launch_bounds__(256) void tilesum_kernel(const int* __restrict__ deg,
                                                      int* __restrict__ tsum, int N) {
  __shared__ int ws[4];
  int tid = threadIdx.x;
  int i = blockIdx.x * 256 + tid;
  int v = (i < N) ? deg[i] : 0;
#pragma unroll
  for (int off = 32; off > 0; off >>= 1) v += __shfl_down(v, off, 64);
  if ((tid & 63) == 0) ws[tid >> 6] = v;
  __syncthreads();
  if (tid == 0) tsum[blockIdx.x] = ws[0] + ws[1] + ws[2] + ws[3];
}

__global__ __launch_bounds__(256) void tscan_kernel(const int* __restrict__ tsum,
                                                    int* __restrict__ texcl,
                                                    int* __restrict__ startN, int nt_) {
  __shared__ int wsum[4];
  int tid = threadIdx.x, lane = tid & 63, w = tid >> 6;
  int v = (tid < nt_) ? tsum[tid] : 0;
  int s = v;
#pragma unroll
  for (int off = 1; off < 64; off <<= 1) {
    int t = __shfl_up(s, off, 64);
    if (lane >= off) s += t;
  }
  if (lane == 63) wsum[w] = s;
  __syncthreads();
  int add = 0;
  for (int j = 0; j < w; ++j) add += wsum[j];
  if (tid < nt_) texcl[tid] = add + s - v;
  if (tid == 0) *startN = wsum[0] + wsum[1] + wsum[2] + wsum[3];  // = E
}

__global__ __launch_bounds__(256) void scanout_kernel(const int* __restrict__ deg,
                                                      const int* __restrict__ texcl,
                                                      int* __restrict__ start,
                                                      int* __restrict__ cursor, int N) {
  __shared__ int wsum[4];
  int tid = threadIdx.x, lane = tid & 63, w = tid >> 6;
  int i = blockIdx.x * 256 + tid;
  int v = (i < N) ? deg[i] : 0;
  int s = v;
#pragma unroll
  for (int off = 1; off < 64; off <<= 1) {
    int t = __shfl_up(s, off, 64);
    if (lane >= off) s += t;
  }
  if (lane == 63) wsum[w] = s;
  __syncthreads();
  int add = texcl[blockIdx.x];
  for (int j = 0; j < w; ++j) add += wsum[j];
  int excl = add + s - v;
  if (i < N) { start[i] = excl; cursor[i] = excl; }
}

__global__ __launch_bounds__(256) void scatter_kernel(const int* __restrict__ eidx,
                                                      int* __restrict__ cursor,
                                                      int* __restrict__ srow, int E) {
  int i = blockIdx.x * 256 + threadIdx.x;
  if (i < E) {
    int slot = atomicAdd(&cursor[eidx[E + i]], 1);
    srow[slot] = eidx[i];
  }
}

template <typename T>
__device__ __forceinline__ bf16x8 load_frag8(const T* p) {
  bf16x8 r;
  if constexpr (std::is_same<T, float>::value) {
    float4 a = *(const float4*)p;
    float4 b = *(const float4*)(p + 4);
    r[0] = (bf16_t)a.x; r[1] = (bf16_t)a.y; r[2] = (bf16_t)a.z; r[3] = (bf16_t)a.w;
    r[4] = (bf16_t)b.x; r[5] = (bf16_t)b.y; r[6] = (bf16_t)b.z; r[7] = (bf16_t)b.w;
  } else {
    r = *(const bf16x8*)p;
  }
  return r;
}

// ---------------------------------------------------------------------------
// Node GEMM (proven r2/r3): 64 nodes/block, 16 nodes/wave, MFMA 16x16x32.
// ---------------------------------------------------------------------------
template <typename T, bool FINAL>
__global__ __launch_bounds__(256) void node_gemm_kernel(
    const T* __restrict__ xin, const T* __restrict__ W,
    const T* __restrict__ bias, const bf16_t* __restrict__ maxv,
    void* __restrict__ dst, const int* __restrict__ flag, int N)
{
  constexpr bool IS_F32 = std::is_same<T, float>::value;
  if ((*flag != 0) != IS_F32) return;

  __shared__ bf16_t ws_[8][4][64][8];
  __shared__ float  bs_[128];

  const int tid = threadIdx.x;
  for (int it = tid; it < 8 * 4 * 64; it += 256) {
    int nt = it >> 8, kt = (it >> 6) & 3, l = it & 63;
    int n = nt * 16 + (l & 15), quad = l >> 4;
    bf16x8 v;
#pragma unroll
    for (int j = 0; j < 8; ++j) v[j] = (bf16_t)(float)W[(kt * 32 + quad * 8 + j) * 128 + n];
    *(bf16x8*)&ws_[nt][kt][l][0] = v;
  }
  if (tid < 128) bs_[tid] = (float)bias[tid];
  __syncthreads();

  const int w = tid >> 6, lane = tid & 63;
  const int m15 = lane & 15, quad = lane >> 4;

  int node_a = blockIdx.x * 64 + w * 16 + m15;
  const T* xrow = xin + (long)min(node_a, N - 1) * 128;
  bf16x8 a[4];
#pragma unroll
  for (int kt = 0; kt < 4; ++kt)
    a[kt] = load_frag8(xrow + kt * 32 + quad * 8);

  f32x4 acc[8];
#pragma unroll
  for (int nt = 0; nt < 8; ++nt) acc[nt] = (f32x4){0.f, 0.f, 0.f, 0.f};
#pragma unroll
  for (int nt = 0; nt < 8; ++nt)
#pragma unroll
    for (int kt = 0; kt < 4; ++kt)
      acc[nt] = __builtin_amdgcn_mfma_f32_16x16x32_bf16(
          a[kt], *(const bf16x8*)&ws_[nt][kt][lane][0], acc[nt], 0, 0, 0);

#pragma unroll
  for (int r = 0; r < 4; ++r) {
    int node = blockIdx.x * 64 + w * 16 + quad * 4 + r;
    if (node < N) {
#pragma unroll
      for (int nt = 0; nt < 8; ++nt) {
        int c = nt * 16 + m15;
        float v = acc[nt][r] + bs_[c];
        long idx = (long)node * 128 + c;
        if constexpr (FINAL) {
          v += (float)maxv[idx];
          if constexpr (IS_F32) ((float*)dst)[idx] = v;
          else                  ((bf16_t*)dst)[idx] = (bf16_t)v;
        } else {
          ((bf16_t*)dst)[idx] = (bf16_t)v;
        }
      }
    }
  }
}

// ---------------------------------------------------------------------------
// K6 v2: one wave per node; 32 edges per iteration (two 16-row MFMA tiles A/B
// sharing each W2 B-fragment LDS read; nt-paired -> 4 independent MFMA chains).
// W1p lives in a small LDS table (float4 broadcast reads) instead of 96 VGPRs.
// ---------------------------------------------------------------------------
template <typename T>
__global__ __launch_bounds__(256, 4) void pernode_kernel(
    const T* __restrict__ pos, const bf16_t* __restrict__ xw1b,
    const T* __restrict__ W1, const T* __restrict__ W2, const T* __restrict__ b2,
    const int* __restrict__ start, const int* __restrict__ srow,
    bf16_t* __restrict__ maxbf, const int* __restrict__ flag, int N)
{
  constexpr bool IS_F32 = std::is_same<T, float>::value;
  if ((*flag != 0) != IS_F32) return;

  __shared__ bf16_t w2s[8][4][64][8];   // 32 KB, B-fragment-major
  __shared__ float  w1pf[4][4][3][8];   // [kt][quad][d][j], 1.5 KB
  __shared__ float  b2s[128];

  const int tid = threadIdx.x;
  for (int it = tid; it < 8 * 4 * 64; it += 256) {
    int nt = it >> 8, kt = (it >> 6) & 3, l = it & 63;
    int ncol = nt * 16 + (l & 15), q = l >> 4;
    bf16x8 v;
#pragma unroll
    for (int j = 0; j < 8; ++j) v[j] = (bf16_t)(float)W2[(kt * 32 + q * 8 + j) * 128 + ncol];
    *(bf16x8*)&w2s[nt][kt][l][0] = v;
  }
  for (int it = tid; it < 384; it += 256) {
    int kt = it / 96, rem = it % 96, q = rem / 24, d = (rem % 24) >> 3, j = it & 7;
    w1pf[kt][q][d][j] = (float)W1[(128 + d) * 128 + kt * 32 + q * 8 + j];
  }
  if (tid < 128) b2s[tid] = (float)b2[tid];
  __syncthreads();

  const int w = tid >> 6, lane = tid & 63;
  const int m15 = lane & 15, quad = lane >> 4;

  for (int n = blockIdx.x * 4 + w; n < N; n += gridDim.x * 4) {
    const int s = start[n], e = start[n + 1];
    if (e <= s) {                      // empty segment -> 0
      if (quad == 0) {
#pragma unroll
        for (int nt = 0; nt < 8; ++nt)
          maxbf[(long)n * 128 + nt * 16 + m15] = (bf16_t)0.f;
      }
      continue;
    }
    const float pn0 = (float)pos[n * 3 + 0];
    const float pn1 = (float)pos[n * 3 + 1];
    const float pn2 = (float)pos[n * 3 + 2];

    float runmax[8];
#pragma unroll
    for (int nt = 0; nt < 8; ++nt) runmax[nt] = -3.4e38f;

    int rA = srow[min(s + m15, e - 1)];        // pad = duplicate last edge
    int rB = srow[min(s + 16 + m15, e - 1)];

    for (int c = s; c < e; c += 32) {
      // prefetch next pair's row indices (hides srow->pos/xv chain head)
      int rA2 = rA, rB2 = rB;
      if (c + 32 < e) {
        rA2 = srow[min(c + 32 + m15, e - 1)];
        rB2 = srow[min(c + 48 + m15, e - 1)];
      }
      const float a0 = (float)pos[rA * 3 + 0] - pn0;
      const float a1 = (float)pos[rA * 3 + 1] - pn1;
      const float a2 = (float)pos[rA * 3 + 2] - pn2;
      const float g0 = (float)pos[rB * 3 + 0] - pn0;
      const float g1 = (float)pos[rB * 3 + 1] - pn1;
      const float g2 = (float)pos[rB * 3 + 2] - pn2;
      const bf16_t* xrA = xw1b + (long)rA * 128;
      const bf16_t* xrB = xw1b + (long)rB * 128;

      bf16x8 fA[4], fB[4];
#pragma unroll
      for (int kt = 0; kt < 4; ++kt) {
        bf16x8 xvA = *(const bf16x8*)(xrA + kt * 32 + quad * 8);
        bf16x8 xvB = *(const bf16x8*)(xrB + kt * 32 + quad * 8);
        const float* wp = &w1pf[kt][quad][0][0];  // 24 floats, quad-broadcast
#pragma unroll
        for (int j = 0; j < 8; ++j) {
          float w0 = wp[j], w1 = wp[8 + j], w2v = wp[16 + j];
          float hA = (float)xvA[j] + a0 * w0 + a1 * w1 + a2 * w2v;
          float hB = (float)xvB[j] + g0 * w0 + g1 * w1 + g2 * w2v;
          fA[kt][j] = (bf16_t)fmaxf(hA, 0.f);
          fB[kt][j] = (bf16_t)fmaxf(hB, 0.f);
        }
      }

#pragma unroll
      for (int nt = 0; nt < 8; nt += 2) {      // nt-paired: 4 indep MFMA chains
        f32x4 aA0 = (f32x4){0.f,0.f,0.f,0.f}, aB0 = aA0, aA1 = aA0, aB1 = aA0;
#pragma unroll
        for (int kt = 0; kt < 4; ++kt) {
          bf16x8 b0 = *(const bf16x8*)&w2s[nt][kt][lane][0];
          bf16x8 b1 = *(const bf16x8*)&w2s[nt + 1][kt][lane][0];
          aA0 = __builtin_amdgcn_mfma_f32_16x16x32_bf16(fA[kt], b0, aA0, 0, 0, 0);
          aB0 = __builtin_amdgcn_mfma_f32_16x16x32_bf16(fB[kt], b0, aB0, 0, 0, 0);
          aA1 = __builtin_amdgcn_mfma_f32_16x16x32_bf16(fA[kt], b1, aA1, 0, 0, 0);
          aB1 = __builtin_amdgcn_mfma_f32_16x16x32_bf16(fB[kt], b1, aB1, 0, 0, 0);
        }
        runmax[nt]     = fmaxf(runmax[nt],     fmaxf(fmaxf(aA0[0], aA0[1]), fmaxf(aA0[2], aA0[3])));
        runmax[nt]     = fmaxf(runmax[nt],     fmaxf(fmaxf(aB0[0], aB0[1]), fmaxf(aB0[2], aB0[3])));
        runmax[nt + 1] = fmaxf(runmax[nt + 1], fmaxf(fmaxf(aA1[0], aA1[1]), fmaxf(aA1[2], aA1[3])));
        runmax[nt + 1] = fmaxf(runmax[nt + 1], fmaxf(fmaxf(aB1[0], aB1[1]), fmaxf(aB1[2], aB1[3])));
      }
      rA = rA2; rB = rB2;
    }

    // cross-quad reduction; cols = nt*16 + m15
#pragma unroll
    for (int nt = 0; nt < 8; ++nt) {
      float v = runmax[nt];
      v = fmaxf(v, __shfl_xor(v, 16, 64));
      v = fmaxf(v, __shfl_xor(v, 32, 64));
      v += b2s[nt * 16 + m15];
      if (quad == 0) maxbf[(long)n * 128 + nt * 16 + m15] = (bf16_t)v;
    }
  }
}

extern "C" void kernel_launch(void* const* d_in, const int* in_sizes, int n_in,
                              void* d_out, int out_size, void* d_ws, size_t ws_size,
                              hipStream_t stream) {
  (void)n_in; (void)ws_size; (void)out_size;
  const void* x   = d_in[0];
  const void* pos = d_in[1];
  const int*  eix = (const int*)d_in[2];
  const void* W1  = d_in[3];  // 131 x 128
  const void* b1  = d_in[4];
  const void* W2  = d_in[5];
  const void* b2  = d_in[6];
  const void* Wr  = d_in[7];
  const void* br  = d_in[8];

  const int N = in_sizes[0] / 128;
  const int E = in_sizes[2] / 2;

  bf16_t* maxbf  = (bf16_t*)d_ws;
  int*    srow   = (int*)((char*)d_ws + (size_t)N * 256);
  int*    deg    = srow + E;
  int*    start  = deg + N;
  int*    cursor = start + N + 1;
  int*    flag   = cursor + N;
  int*    tsum   = flag + 1;
  int*    texcl  = tsum + 256;
  bf16_t* xw1b   = (bf16_t*)d_out;   // d_out doubles as bf16 scratch until K7

  const int nTiles = (N + 255) / 256;   // 196 <= 256

  detect_kernel<<<1, 64, 0, stream>>>((const unsigned*)x, flag);
  hipMemsetAsync(deg, 0, (size_t)N * 4, stream);
  hist_kernel<<<(E + 255) / 256, 256, 0, stream>>>(eix, deg, E);
  tilesum_kernel<<<nTiles, 256, 0, stream>>>(deg, tsum, N);
  tscan_kernel<<<1, 256, 0, stream>>>(tsum, texcl, &start[N], nTiles);
  scanout_kernel<<<nTiles, 256, 0, stream>>>(deg, texcl, start, cursor, N);
  scatter_kernel<<<(E + 255) / 256, 256, 0, stream>>>(eix, cursor, srow, E);

  const int nodeBlocks = (N + 63) / 64;
  node_gemm_kernel<bf16_t, false><<<nodeBlocks, 256, 0, stream>>>(
      (const bf16_t*)x, (const bf16_t*)W1, (const bf16_t*)b1, nullptr, xw1b, flag, N);
  node_gemm_kernel<float, false><<<nodeBlocks, 256, 0, stream>>>(
      (const float*)x, (const float*)W1, (const float*)b1, nullptr, xw1b, flag, N);

  pernode_kernel<bf16_t><<<2048, 256, 0, stream>>>(
      (const bf16_t*)pos, xw1b, (const bf16_t*)W1, (const bf16_t*)W2,
      (const bf16_t*)b2, start, srow, maxbf, flag, N);
  pernode_kernel<float><<<2048, 256, 0, stream>>>(
      (const float*)pos, xw1b, (const float*)W1, (const float*)W2,
      (const float*)b2, start, srow, maxbf, flag, N);

  node_gemm_kernel<bf16_t, true><<<nodeBlocks, 256, 0, stream>>>(
      (const bf16_t*)x, (const bf16_t*)Wr, (const bf16_t*)br, maxbf, d_out, flag, N);
  node_gemm_kernel<float, true><<<nodeBlocks, 256, 0, stream>>>(
      (const float*)x, (const float*)Wr, (const float*)br, maxbf, d_out, flag, N);
}

// Round 5
// 573.843 us; speedup vs baseline: 3.7087x; 3.7087x over previous
//
#include <hip/hip_runtime.h>
#include <hip/hip_bf16.h>

// PointNetConv on MI355X (gfx950) — round 5. f32 inputs (measured r3/r4).
//   deg=0 (memset) ; hist ; 3-phase scan ; scatter  -> edges sorted by dest
//   K5 node_gemm<false>: xw1b(bf16, in d_out) = x @ W1x + b1
//   K6 pernode: one wave per node, 16 edges/chunk, one-chunk-ahead software
//               pipeline (srow/pos/xw1b prefetch), MFMA 16x16x32, reg max.
//   K7 node_gemm<true> : d_out = maxbf + x @ Wr + br
//
// ws: maxbf N*128 bf16 (12.8MB) | srow E int (6.4MB) | deg N | start N+1 |
//     cursor N | tsum 256 | texcl 256   (~20 MB). xw1b lives in d_out[0:12.8MB].

typedef __bf16 bf16_t;
typedef __bf16 bf16x8 __attribute__((ext_vector_type(8)));
typedef float  f32x4  __attribute__((ext_vector_type(4)));

__global__ __launch_bounds__(256) void hist_kernel(const int* __restrict__ eidx,
                                                   int* __restrict__ deg, int E) {
  int i = blockIdx.x * 256 + threadIdx.x;
  if (i < E) atomicAdd(&deg[eidx[E + i]], 1);
}

// --- 3-phase exclusive scan (N <= 256*256), proven round 4 ---
__global__ __launch_bounds__(256) void tilesum_kernel(const int* __restrict__ deg,
                                                      int* __restrict__ tsum, int N) {
  __shared__ int ws[4];
  int tid = threadIdx.x;
  int i = blockIdx.x * 256 + tid;
  int v = (i < N) ? deg[i] : 0;
#pragma unroll
  for (int off = 32; off > 0; off >>= 1) v += __shfl_down(v, off, 64);
  if ((tid & 63) == 0) ws[tid >> 6] = v;
  __syncthreads();
  if (tid == 0) tsum[blockIdx.x] = ws[0] + ws[1] + ws[2] + ws[3];
}

__global__ __launch_bounds__(256) void tscan_kernel(const int* __restrict__ tsum,
                                                    int* __restrict__ texcl,
                                                    int* __restrict__ startN, int nt_) {
  __shared__ int wsum[4];
  int tid = threadIdx.x, lane = tid & 63, w = tid >> 6;
  int v = (tid < nt_) ? tsum[tid] : 0;
  int s = v;
#pragma unroll
  for (int off = 1; off < 64; off <<= 1) {
    int t = __shfl_up(s, off, 64);
    if (lane >= off) s += t;
  }
  if (lane == 63) wsum[w] = s;
  __syncthreads();
  int add = 0;
  for (int j = 0; j < w; ++j) add += wsum[j];
  if (tid < nt_) texcl[tid] = add + s - v;
  if (tid == 0) *startN = wsum[0] + wsum[1] + wsum[2] + wsum[3];  // = E
}

__global__ __launch_bounds__(256) void scanout_kernel(const int* __restrict__ deg,
                                                      const int* __restrict__ texcl,
                                                      int* __restrict__ start,
                                                      int* __restrict__ cursor, int N) {
  __shared__ int wsum[4];
  int tid = threadIdx.x, lane = tid & 63, w = tid >> 6;
  int i = blockIdx.x * 256 + tid;
  int v = (i < N) ? deg[i] : 0;
  int s = v;
#pragma unroll
  for (int off = 1; off < 64; off <<= 1) {
    int t = __shfl_up(s, off, 64);
    if (lane >= off) s += t;
  }
  if (lane == 63) wsum[w] = s;
  __syncthreads();
  int add = texcl[blockIdx.x];
  for (int j = 0; j < w; ++j) add += wsum[j];
  int excl = add + s - v;
  if (i < N) { start[i] = excl; cursor[i] = excl; }
}

__global__ __launch_bounds__(256) void scatter_kernel(const int* __restrict__ eidx,
                                                      int* __restrict__ cursor,
                                                      int* __restrict__ srow, int E) {
  int i = blockIdx.x * 256 + threadIdx.x;
  if (i < E) {
    int slot = atomicAdd(&cursor[eidx[E + i]], 1);
    srow[slot] = eidx[i];
  }
}

__device__ __forceinline__ bf16x8 load_frag8f(const float* p) {
  float4 a = *(const float4*)p;
  float4 b = *(const float4*)(p + 4);
  bf16x8 r;
  r[0] = (bf16_t)a.x; r[1] = (bf16_t)a.y; r[2] = (bf16_t)a.z; r[3] = (bf16_t)a.w;
  r[4] = (bf16_t)b.x; r[5] = (bf16_t)b.y; r[6] = (bf16_t)b.z; r[7] = (bf16_t)b.w;
  return r;
}

// ---------------------------------------------------------------------------
// Node GEMM (proven r2-r4): 64 nodes/block, 16 nodes/wave, MFMA 16x16x32.
// FINAL=false: dst = bf16 xw1b = x @ W + bias ; FINAL=true: dst = f32 out.
// ---------------------------------------------------------------------------
template <bool FINAL>
__global__ __launch_bounds__(256) void node_gemm_kernel(
    const float* __restrict__ xin, const float* __restrict__ W,
    const float* __restrict__ bias, const bf16_t* __restrict__ maxv,
    void* __restrict__ dst, int N)
{
  __shared__ bf16_t ws_[8][4][64][8];   // B-fragment-major, 32 KB
  __shared__ float  bs_[128];

  const int tid = threadIdx.x;
  for (int it = tid; it < 8 * 4 * 64; it += 256) {
    int nt = it >> 8, kt = (it >> 6) & 3, l = it & 63;
    int n = nt * 16 + (l & 15), quad = l >> 4;
    bf16x8 v;
#pragma unroll
    for (int j = 0; j < 8; ++j) v[j] = (bf16_t)W[(kt * 32 + quad * 8 + j) * 128 + n];
    *(bf16x8*)&ws_[nt][kt][l][0] = v;
  }
  if (tid < 128) bs_[tid] = bias[tid];
  __syncthreads();

  const int w = tid >> 6, lane = tid & 63;
  const int m15 = lane & 15, quad = lane >> 4;

  int node_a = blockIdx.x * 64 + w * 16 + m15;
  const float* xrow = xin + (long)min(node_a, N - 1) * 128;
  bf16x8 a[4];
#pragma unroll
  for (int kt = 0; kt < 4; ++kt)
    a[kt] = load_frag8f(xrow + kt * 32 + quad * 8);

  f32x4 acc[8];
#pragma unroll
  for (int nt = 0; nt < 8; ++nt) acc[nt] = (f32x4){0.f, 0.f, 0.f, 0.f};
#pragma unroll
  for (int nt = 0; nt < 8; ++nt)
#pragma unroll
    for (int kt = 0; kt < 4; ++kt)
      acc[nt] = __builtin_amdgcn_mfma_f32_16x16x32_bf16(
          a[kt], *(const bf16x8*)&ws_[nt][kt][lane][0], acc[nt], 0, 0, 0);

#pragma unroll
  for (int r = 0; r < 4; ++r) {
    int node = blockIdx.x * 64 + w * 16 + quad * 4 + r;
    if (node < N) {
#pragma unroll
      for (int nt = 0; nt < 8; ++nt) {
        int c = nt * 16 + m15;
        float v = acc[nt][r] + bs_[c];
        long idx = (long)node * 128 + c;
        if constexpr (FINAL) {
          v += (float)maxv[idx];
          ((float*)dst)[idx] = v;
        } else {
          ((bf16_t*)dst)[idx] = (bf16_t)v;
        }
      }
    }
  }
}

// ---------------------------------------------------------------------------
// K6: one wave per node; 16 edges/chunk; ONE-CHUNK-AHEAD software pipeline:
// next chunk's srow/pos/xw1b loads issue before current chunk's h1+MFMA.
// acc in 2 passes of 4 (16 regs) to fund the prefetch registers. No atomics.
// ---------------------------------------------------------------------------
__global__ __launch_bounds__(256) void pernode_kernel(
    const float* __restrict__ pos, const bf16_t* __restrict__ xw1b,
    const float* __restrict__ W1, const float* __restrict__ W2,
    const float* __restrict__ b2, const int* __restrict__ start,
    const int* __restrict__ srow, bf16_t* __restrict__ maxbf, int N)
{
  __shared__ bf16_t w2s[8][4][64][8];   // 32 KB, B-fragment-major
  __shared__ float  w1pf[4][4][3][8];   // [kt][quad][d][j], 1.5 KB
  __shared__ float  b2s[128];

  const int tid = threadIdx.x;
  for (int it = tid; it < 8 * 4 * 64; it += 256) {
    int nt = it >> 8, kt = (it >> 6) & 3, l = it & 63;
    int ncol = nt * 16 + (l & 15), q = l >> 4;
    bf16x8 v;
#pragma unroll
    for (int j = 0; j < 8; ++j) v[j] = (bf16_t)W2[(kt * 32 + q * 8 + j) * 128 + ncol];
    *(bf16x8*)&w2s[nt][kt][l][0] = v;
  }
  for (int it = tid; it < 384; it += 256) {
    int kt = it / 96, rem = it % 96, q = rem / 24, d = (rem % 24) >> 3, j = it & 7;
    w1pf[kt][q][d][j] = W1[(128 + d) * 128 + kt * 32 + q * 8 + j];
  }
  if (tid < 128) b2s[tid] = b2[tid];
  __syncthreads();

  const int w = tid >> 6, lane = tid & 63;
  const int m15 = lane & 15, quad = lane >> 4;

  for (int n = blockIdx.x * 4 + w; n < N; n += gridDim.x * 4) {
    const int s = start[n], e = start[n + 1];
    if (e <= s) {                      // empty segment -> 0
      if (quad == 0) {
#pragma unroll
        for (int nt = 0; nt < 8; ++nt)
          maxbf[(long)n * 128 + nt * 16 + m15] = (bf16_t)0.f;
      }
      continue;
    }
    const float pn0 = pos[n * 3 + 0];
    const float pn1 = pos[n * 3 + 1];
    const float pn2 = pos[n * 3 + 2];

    float runmax[8];
#pragma unroll
    for (int nt = 0; nt < 8; ++nt) runmax[nt] = -3.4e38f;

    // prologue: chunk-0 loads (pad = duplicate last edge; harmless for max)
    int row = srow[min(s + m15, e - 1)];
    float q0 = pos[row * 3 + 0], q1 = pos[row * 3 + 1], q2 = pos[row * 3 + 2];
    bf16x8 xv[4];
#pragma unroll
    for (int kt = 0; kt < 4; ++kt)
      xv[kt] = *(const bf16x8*)(xw1b + (long)row * 128 + kt * 32 + quad * 8);

    for (int c = s; c < e; c += 16) {
      // ---- issue NEXT chunk's loads first (overlaps with compute below) ----
      int nrow = row;
      float nq0, nq1, nq2;
      bf16x8 nxv[4];
      const bool more = (c + 16) < e;   // wave-uniform
      if (more) {
        nrow = srow[min(c + 16 + m15, e - 1)];
        nq0 = pos[nrow * 3 + 0]; nq1 = pos[nrow * 3 + 1]; nq2 = pos[nrow * 3 + 2];
#pragma unroll
        for (int kt = 0; kt < 4; ++kt)
          nxv[kt] = *(const bf16x8*)(xw1b + (long)nrow * 128 + kt * 32 + quad * 8);
      } else {
        nq0 = q0; nq1 = q1; nq2 = q2;
#pragma unroll
        for (int kt = 0; kt < 4; ++kt) nxv[kt] = xv[kt];
      }

      // ---- current chunk: h1 A-fragment build (f32 math, bf16 pack) ----
      const float d0 = q0 - pn0, d1 = q1 - pn1, d2 = q2 - pn2;
      bf16x8 fA[4];
#pragma unroll
      for (int kt = 0; kt < 4; ++kt) {
        const float* wp = &w1pf[kt][quad][0][0];   // 24 floats, quad-broadcast
#pragma unroll
        for (int j = 0; j < 8; ++j) {
          float h = (float)xv[kt][j] + d0 * wp[j] + d1 * wp[8 + j] + d2 * wp[16 + j];
          fA[kt][j] = (bf16_t)fmaxf(h, 0.f);
        }
      }

      // ---- MFMA: two passes of 4 cout-tiles (4 indep chains each) ----
#pragma unroll
      for (int half = 0; half < 2; ++half) {
        f32x4 a0 = (f32x4){0.f, 0.f, 0.f, 0.f}, a1 = a0, a2 = a0, a3 = a0;
#pragma unroll
        for (int kt = 0; kt < 4; ++kt) {
          a0 = __builtin_amdgcn_mfma_f32_16x16x32_bf16(
              fA[kt], *(const bf16x8*)&w2s[half * 4 + 0][kt][lane][0], a0, 0, 0, 0);
          a1 = __builtin_amdgcn_mfma_f32_16x16x32_bf16(
              fA[kt], *(const bf16x8*)&w2s[half * 4 + 1][kt][lane][0], a1, 0, 0, 0);
          a2 = __builtin_amdgcn_mfma_f32_16x16x32_bf16(
              fA[kt], *(const bf16x8*)&w2s[half * 4 + 2][kt][lane][0], a2, 0, 0, 0);
          a3 = __builtin_amdgcn_mfma_f32_16x16x32_bf16(
              fA[kt], *(const bf16x8*)&w2s[half * 4 + 3][kt][lane][0], a3, 0, 0, 0);
        }
        runmax[half * 4 + 0] = fmaxf(runmax[half * 4 + 0],
            fmaxf(fmaxf(a0[0], a0[1]), fmaxf(a0[2], a0[3])));
        runmax[half * 4 + 1] = fmaxf(runmax[half * 4 + 1],
            fmaxf(fmaxf(a1[0], a1[1]), fmaxf(a1[2], a1[3])));
        runmax[half * 4 + 2] = fmaxf(runmax[half * 4 + 2],
            fmaxf(fmaxf(a2[0], a2[1]), fmaxf(a2[2], a2[3])));
        runmax[half * 4 + 3] = fmaxf(runmax[half * 4 + 3],
            fmaxf(fmaxf(a3[0], a3[1]), fmaxf(a3[2], a3[3])));
      }

      // ---- rotate pipeline ----
      row = nrow; q0 = nq0; q1 = nq1; q2 = nq2;
#pragma unroll
      for (int kt = 0; kt < 4; ++kt) xv[kt] = nxv[kt];
    }

    // cross-quad reduction; cols = nt*16 + m15
#pragma unroll
    for (int nt = 0; nt < 8; ++nt) {
      float v = runmax[nt];
      v = fmaxf(v, __shfl_xor(v, 16, 64));
      v = fmaxf(v, __shfl_xor(v, 32, 64));
      v += b2s[nt * 16 + m15];
      if (quad == 0) maxbf[(long)n * 128 + nt * 16 + m15] = (bf16_t)v;
    }
  }
}

extern "C" void kernel_launch(void* const* d_in, const int* in_sizes, int n_in,
                              void* d_out, int out_size, void* d_ws, size_t ws_size,
                              hipStream_t stream) {
  (void)n_in; (void)ws_size; (void)out_size;
  const float* x   = (const float*)d_in[0];
  const float* pos = (const float*)d_in[1];
  const int*   eix = (const int*)d_in[2];
  const float* W1  = (const float*)d_in[3];  // 131 x 128
  const float* b1  = (const float*)d_in[4];
  const float* W2  = (const float*)d_in[5];
  const float* b2  = (const float*)d_in[6];
  const float* Wr  = (const float*)d_in[7];
  const float* br  = (const float*)d_in[8];

  const int N = in_sizes[0] / 128;
  const int E = in_sizes[2] / 2;

  bf16_t* maxbf  = (bf16_t*)d_ws;
  int*    srow   = (int*)((char*)d_ws + (size_t)N * 256);
  int*    deg    = srow + E;
  int*    start  = deg + N;
  int*    cursor = start + N + 1;
  int*    tsum   = cursor + N;
  int*    texcl  = tsum + 256;
  bf16_t* xw1b   = (bf16_t*)d_out;   // d_out (25.6MB f32) hosts bf16 scratch (12.8MB) until K7

  const int nTiles = (N + 255) / 256;   // 196 <= 256

  hipMemsetAsync(deg, 0, (size_t)N * 4, stream);
  hist_kernel<<<(E + 255) / 256, 256, 0, stream>>>(eix, deg, E);
  tilesum_kernel<<<nTiles, 256, 0, stream>>>(deg, tsum, N);
  tscan_kernel<<<1, 256, 0, stream>>>(tsum, texcl, &start[N], nTiles);
  scanout_kernel<<<nTiles, 256, 0, stream>>>(deg, texcl, start, cursor, N);
  scatter_kernel<<<(E + 255) / 256, 256, 0, stream>>>(eix, cursor, srow, E);

  const int nodeBlocks = (N + 63) / 64;
  node_gemm_kernel<false><<<nodeBlocks, 256, 0, stream>>>(x, W1, b1, nullptr, xw1b, N);

  pernode_kernel<<<2048, 256, 0, stream>>>(pos, xw1b, W1, W2, b2, start, srow, maxbf, N);

  node_gemm_kernel<true><<<nodeBlocks, 256, 0, stream>>>(x, Wr, br, maxbf, d_out, N);
}